// Round 5
// baseline (2570.988 us; speedup 1.0000x reference)
//
#include <hip/hip_runtime.h>
#include <hip/hip_bf16.h>
#include <math.h>

// ---------------- problem constants ----------------
#define TT   128      // timesteps
#define BB   128      // batch
#define UU   512      // LSTM units
#define EMBD 300      // embedding dim
#define EMBP 320      // padded embedding dim (multiple of 32 for MFMA K)
#define NBLK 192      // 2 dir x 3 layers x 32 column-blocks (1 block/CU, 16 h-cols each)
#define DBLK 96       // blocks per direction
#define NTHR 512      // 8 waves = (4 row-groups x 2 col-halves), 2x2 16-tiles each
#define BSTR 1032     // Bt row stride el (2064 B = 16 mod 128 -> uniform 8-window b128 reads)
#define ZST  34       // zbuf row stride (f32): 2 lanes/bank on transpose stores

using bf16x8 = __attribute__((ext_vector_type(8))) short;
using f32x4  = __attribute__((ext_vector_type(4))) float;

// ws layout: flags 768B | epoch @4096 | X 10MB | H 6 slots (write-once!) | hf
#define NEED_WS 111681536ull
static void* g_pool = nullptr;
__attribute__((constructor)) static void alloc_pool() {
    if (hipMalloc(&g_pool, 120ull * 1024ull * 1024ull) != hipSuccess) g_pool = nullptr;
}

__device__ __forceinline__ float b2f(unsigned short u) {
    union { unsigned int i; float f; } v; v.i = ((unsigned int)u) << 16; return v.f;
}
__device__ __forceinline__ unsigned short f2b(float f) {
    union { unsigned int i; float f; } v; v.f = f;
    unsigned int i = v.i;
    return (unsigned short)((i + 0x7fffu + ((i >> 16) & 1u)) >> 16);  // RNE
}
__device__ __forceinline__ unsigned short ld_bf(const void* p, size_t i, int f32) {
    return f32 ? f2b(((const float*)p)[i]) : ((const unsigned short*)p)[i];
}
__device__ __forceinline__ float ld_f(const void* p, size_t i, int f32) {
    return f32 ? ((const float*)p)[i] : b2f(((const unsigned short*)p)[i]);
}
__device__ __forceinline__ float clampz(float x) {
    return fminf(fmaxf(x, -60.0f), 60.0f);
}
__device__ __forceinline__ float sigm(float x)  { return 1.0f / (1.0f + __expf(-x)); }
__device__ __forceinline__ float ssign(float x) { return x / (1.0f + fabsf(x)); }

__device__ __forceinline__ int detect_f32(const void* emb) {
    const unsigned int* w = (const unsigned int*)emb;
    int cnt = 0;
    #pragma unroll
    for (int i = 0; i < 64; ++i) {
        unsigned int e = (w[i] >> 23) & 0xFFu;
        cnt += (e >= 96u && e <= 159u) ? 1 : 0;
    }
    return cnt >= 48;
}

struct P {
    const int* ids;
    const void* emb;
    const void* Wm[2][3];
    const void* Um[2][3];
    const void* bm[2][3];
    const void *d0W, *d0b;
    const void *bn_gamma, *bn_beta, *bn_mean, *bn_var;
    const void *alpha, *d1W, *d1b;
    unsigned short* X;      // [TT][BB][EMBP] bf16 (written once, fence-full barrier after)
    unsigned short* H;      // [3 slots][2 dirs][TT][BB][UU] bf16 — WRITE-ONCE, write-through
    float* hf;              // [2][BB][UU] fp32 — write-through
    unsigned int* flags;    // [NBLK] per-block generation flags
    unsigned int* epoch;    // epoch[0]=dir0, epoch[64]=dir1 (separate lines)
    float* out;             // [BB][7] fp32
};

#define EPOFF 64   // dir1 epoch word offset (256 B from dir0)

__device__ __forceinline__ unsigned int ald(const unsigned int* a) {
    return __hip_atomic_load(a, __ATOMIC_RELAXED, __HIP_MEMORY_SCOPE_AGENT);
}
__device__ __forceinline__ void ast(unsigned int* a, unsigned int v) {
    __hip_atomic_store(a, v, __ATOMIC_RELAXED, __HIP_MEMORY_SCOPE_AGENT);
}

// fence-FULL flat barrier (phase 0 only; X uses normal cached stores)
__device__ __forceinline__ void gsync_fence(unsigned int* flags, unsigned int gen) {
    __syncthreads();
    if (threadIdx.x == 0) {
        __threadfence();
        ast(&flags[blockIdx.x], gen);
    }
    if (threadIdx.x < 64) {
        const int i = threadIdx.x;
        for (;;) {
            bool ok = true;
            #pragma unroll
            for (int j = 0; j < NBLK / 64; ++j)
                ok = ok && (ald(&flags[i + j * 64]) >= gen);
            if (__all(ok)) break;
            __builtin_amdgcn_s_sleep(1);
        }
        __threadfence();
    }
    __syncthreads();
}

// Two-level aggregated per-direction barrier (fence-free; data is
// write-through + write-once). Leaves store own flag; the direction's
// aggregator block polls its 96 flags and publishes one epoch word;
// everyone polls that single word (same-address broadcast load).
__device__ __forceinline__ void gsync_dir(P& p, int dirbase, int eidx, int isagg, unsigned int gen) {
    __syncthreads();
    if (threadIdx.x == 0)
        ast(&p.flags[blockIdx.x], gen);
    if (isagg && threadIdx.x < 64) {
        const unsigned int* f = p.flags + dirbase + threadIdx.x;
        const bool two = (threadIdx.x < DBLK - 64);
        for (;;) {
            bool ok = (ald(f) >= gen) && (!two || (ald(f + 64) >= gen));
            if (__all(ok)) break;
            __builtin_amdgcn_s_sleep(1);
        }
        if (threadIdx.x == 0)
            ast(&p.epoch[eidx], gen);
    }
    if (threadIdx.x < 64) {
        const unsigned int* e = &p.epoch[eidx];
        while (ald(e) < gen) __builtin_amdgcn_s_sleep(1);
    }
    __syncthreads();
}

// full-grid aggregated barrier (before head)
__device__ __forceinline__ void gsync_all(P& p, int dirbase, int eidx, int isagg, unsigned int gen) {
    __syncthreads();
    if (threadIdx.x == 0)
        ast(&p.flags[blockIdx.x], gen);
    if (isagg && threadIdx.x < 64) {
        const unsigned int* f = p.flags + dirbase + threadIdx.x;
        const bool two = (threadIdx.x < DBLK - 64);
        for (;;) {
            bool ok = (ald(f) >= gen) && (!two || (ald(f + 64) >= gen));
            if (__all(ok)) break;
            __builtin_amdgcn_s_sleep(1);
        }
        if (threadIdx.x == 0)
            ast(&p.epoch[eidx], gen);
    }
    if (threadIdx.x < 64) {
        while (!((ald(&p.epoch[0]) >= gen) && (ald(&p.epoch[EPOFF]) >= gen)))
            __builtin_amdgcn_s_sleep(1);
    }
    __syncthreads();
}

// one K-segment of z += A @ B for a 2x2 tile group: A-frags (2 row-tiles)
// shared across B-frags (2 col-tiles) -> 1:1 load:MFMA with half the LDS
// traffic of the 1x4 layout. K1T compile-time; BOFF = column offset in Bt.
template<int K1T, int BOFF>
__device__ __forceinline__ void mfma_part(
    const unsigned short* __restrict__ a0p,    // A row-tile 0 (+ko)
    const unsigned short* __restrict__ a1p,    // A row-tile 1 (+ko)
    const unsigned short* __restrict__ bp0,    // &Bt[nh*32 + l15][ko]
    const unsigned short* __restrict__ bp1,    // &Bt[nh*32 + 16 + l15][ko]
    f32x4 (&acc)[2][2])
{
    #pragma unroll 4
    for (int kt = 0; kt < K1T; kt += 32) {
        bf16x8 av0 = *(const bf16x8*)(a0p + kt);
        bf16x8 av1 = *(const bf16x8*)(a1p + kt);
        bf16x8 bv0 = *(const bf16x8*)(bp0 + BOFF + kt);
        bf16x8 bv1 = *(const bf16x8*)(bp1 + BOFF + kt);
        acc[0][0] = __builtin_amdgcn_mfma_f32_16x16x32_bf16(av0, bv0, acc[0][0], 0, 0, 0);
        acc[0][1] = __builtin_amdgcn_mfma_f32_16x16x32_bf16(av0, bv1, acc[0][1], 0, 0, 0);
        acc[1][0] = __builtin_amdgcn_mfma_f32_16x16x32_bf16(av1, bv0, acc[1][0], 0, 0, 0);
        acc[1][1] = __builtin_amdgcn_mfma_f32_16x16x32_bf16(av1, bv1, acc[1][1], 0, 0, 0);
    }
}

__global__ __launch_bounds__(NTHR, 1) void bilstm_persistent(P p) {
    const int blk = blockIdx.x;
    const int tid = threadIdx.x;

    const int f32 = detect_f32(p.emb);
    unsigned int gen = 0;

    __shared__ __align__(16) unsigned short Bt[64][BSTR];  // B panel [n][k] (129 KB)
    __shared__ __align__(16) float zbuf[8][16 * ZST];      // per-wave transpose (17 KB)
    __shared__ float hact[256];
    __shared__ float lgts[8];

    // ---------------- phase 0: embedding gather (normal stores) ----------------
    for (int row = blk; row < TT * BB; row += NBLK) {
        int t = row >> 7, b = row & 127;
        int id = p.ids[b * TT + t];
        unsigned short* xr = p.X + (size_t)row * EMBP;
        for (int k2 = tid; k2 < EMBP; k2 += NTHR)
            xr[k2] = (k2 < EMBD) ? ld_bf(p.emb, (size_t)id * EMBD + k2, f32)
                                 : (unsigned short)0;
    }
    gsync_fence(p.flags, ++gen);             // only fence-full barrier in the kernel

    // block responsibilities: dir, layer (wavefront-pipelined), 16 h-cols, M=128
    const int dir     = (blk >= DBLK) ? 1 : 0;
    const int rb      = blk - dir * DBLK;
    const int layer   = rb >> 5;             // 0,1,2
    const int dirbase = dir * DBLK;
    const int eidx    = dir * EPOFF;
    const int isagg   = (rb == 0);
    const int j0      = (rb & 31) * 16;      // 16 h-cols per block

    const int wv   = tid >> 6;               // wave 0..7
    const int lane = tid & 63;
    const int l15  = lane & 15;
    const int quad = lane >> 4;
    const int ko   = quad * 8;

    const int mt   = wv >> 1;                // row group: rows mt*32 .. +31
    const int nh   = wv & 1;                 // col half: local h-cols nh*8 .. +7

    // gate-phase mapping (within wave): row crow = lane>>2 (of 16),
    // h-col pair hc0 = (lane&3)*2  -> per row 4 lanes x 4B = 16B contiguous store
    const int crow = lane >> 2;
    const int hc0  = (lane & 3) * 2;

    float cS[2][2];                          // cell state: [row-subtile a][hh]
    cS[0][0] = cS[0][1] = cS[1][0] = cS[1][1] = 0.0f;

    const size_t seq = (size_t)TT * BB * UU;

    // ---- stage this block's B panel (64 gate-cols, its layer) into LDS — ONCE ----
    // column order n = nh*32 + g*8 + h  (so each 32-col half has all 4 gates
    // for 8 h-cols -> wave-private gates)
    const int KW   = (layer == 0) ? EMBD : UU;
    const int K1   = (layer == 0) ? EMBP : UU;
    const int Ktot = K1 + UU;
    const void* Wmat = p.Wm[dir][layer];
    const void* Umat = p.Um[dir][layer];
    const void* bias = p.bm[dir][layer];
    {
        int n = tid >> 3, ks = tid & 7;                          // 8 threads per gate-col row
        int wcol = ((n >> 3) & 3) * 512 + j0 + (n >> 5) * 8 + (n & 7);  // gate*512 + j0 + nh*8 + h
        for (int k2 = ks; k2 < Ktot; k2 += 8) {
            unsigned short v;
            if (k2 < KW)      v = ld_bf(Wmat, (size_t)k2 * 2048 + wcol, f32);
            else if (k2 < K1) v = 0;
            else              v = ld_bf(Umat, (size_t)(k2 - K1) * 2048 + wcol, f32);
            Bt[n][k2] = v;
        }
    }
    // per-lane bias: gates g, h-cols j0 + nh*8 + hc0 + hh
    float bz[4][2];
    #pragma unroll
    for (int g = 0; g < 4; ++g) {
        bz[g][0] = ld_f(bias, g * UU + j0 + nh * 8 + hc0,     f32);
        bz[g][1] = ld_f(bias, g * UU + j0 + nh * 8 + hc0 + 1, f32);
    }
    __syncthreads();

    // write-once slots: layer l writes slot l, reads slot l-1
    unsigned short*       Hl  = p.H + (size_t)(layer * 2 + dir) * seq;
    const unsigned short* Hin = (layer > 0) ? (p.H + (size_t)((layer - 1) * 2 + dir) * seq) : nullptr;

    const unsigned short* bp0 = &Bt[nh * 32 + l15][ko];
    const unsigned short* bp1 = &Bt[nh * 32 + 16 + l15][ko];
    float* zbw = &zbuf[wv][0];

    // ---------------- wavefront-pipelined step loop: 130 barriers/dir ----------------
    for (int s = 0; s < TT + 2; ++s) {
        const int t = s - layer;             // this layer's timestep at wavefront step s
        if (t >= 0 && t < TT) {
            const unsigned short* A2 = (t > 0) ? (Hl + (size_t)(t - 1) * BB * UU) : nullptr;

            f32x4 acc[2][2];
            #pragma unroll
            for (int a = 0; a < 2; ++a) {
                acc[a][0] = f32x4{0.f, 0.f, 0.f, 0.f};
                acc[a][1] = f32x4{0.f, 0.f, 0.f, 0.f};
            }

            if (layer == 0) {
                int tx = dir ? (TT - 1 - t) : t;
                const unsigned short* A1 = p.X + (size_t)tx * BB * EMBP;
                const unsigned short* a0 = A1 + (size_t)(mt * 32 + l15) * EMBP + ko;
                mfma_part<EMBP, 0>(a0, a0 + 16 * EMBP, bp0, bp1, acc);
                if (A2) {
                    const unsigned short* c0 = A2 + (size_t)(mt * 32 + l15) * UU + ko;
                    mfma_part<UU, EMBP>(c0, c0 + 16 * UU, bp0, bp1, acc);
                }
            } else {
                const unsigned short* A1 = Hin + (size_t)t * BB * UU;
                const unsigned short* a0 = A1 + (size_t)(mt * 32 + l15) * UU + ko;
                mfma_part<UU, 0>(a0, a0 + 16 * UU, bp0, bp1, acc);
                if (A2) {
                    const unsigned short* c0 = A2 + (size_t)(mt * 32 + l15) * UU + ko;
                    mfma_part<UU, UU>(c0, c0 + 16 * UU, bp0, bp1, acc);
                }
            }

            // ---- gates: two row-subtile passes, wave-private LDS transpose ----
            // D layout: col = lane&15, row = quad*4 + reg  (m89-verified)
            #pragma unroll
            for (int a = 0; a < 2; ++a) {
                #pragma unroll
                for (int b = 0; b < 2; ++b)
                    #pragma unroll
                    for (int r = 0; r < 4; ++r)
                        zbw[(quad * 4 + r) * ZST + b * 16 + l15] = acc[a][b][r];
                // in-order DS pipe: wave-level write->read needs no barrier
                const int R = mt * 32 + a * 16 + crow;
                float hv[2];
                #pragma unroll
                for (int hh = 0; hh < 2; ++hh) {
                    float zi = clampz(zbw[crow * ZST +  0 + hc0 + hh] + bz[0][hh]);
                    float zf = clampz(zbw[crow * ZST +  8 + hc0 + hh] + bz[1][hh]);
                    float zg = clampz(zbw[crow * ZST + 16 + hc0 + hh] + bz[2][hh]);
                    float zo = clampz(zbw[crow * ZST + 24 + hc0 + hh] + bz[3][hh]);
                    float cp = (t == 0) ? 0.0f : cS[a][hh];
                    float cn = sigm(zf) * cp + sigm(zi) * ssign(zg);
                    cS[a][hh] = cn;
                    hv[hh] = sigm(zo) * ssign(cn);
                }
                // packed write-through store: per inst 16 rows x 16B contiguous/row
                const int col = j0 + nh * 8 + hc0;
                unsigned int pk = (unsigned int)f2b(hv[0]) | ((unsigned int)f2b(hv[1]) << 16);
                __hip_atomic_store((unsigned int*)&Hl[(size_t)t * BB * UU + (size_t)R * UU + col],
                                   pk, __ATOMIC_RELAXED, __HIP_MEMORY_SCOPE_AGENT);
                if (layer == 2 && t == TT - 1) {
                    size_t o = (size_t)dir * BB * UU + (size_t)R * UU + col;
                    __hip_atomic_store(&p.hf[o],     hv[0], __ATOMIC_RELAXED, __HIP_MEMORY_SCOPE_AGENT);
                    __hip_atomic_store(&p.hf[o + 1], hv[1], __ATOMIC_RELAXED, __HIP_MEMORY_SCOPE_AGENT);
                }
            }
        }
        gsync_dir(p, dirbase, eidx, isagg, ++gen);
    }

    gsync_all(p, dirbase, eidx, isagg, ++gen);   // both dirs' hf complete before head

    // ---------------- head: block b handles batch row b (all fp32) ----------------
    if (blk < BB) {
        const int b = blk;
        if (tid < 256) {
            const float* h0 = p.hf + (size_t)b * UU;
            const float* h1 = p.hf + (size_t)BB * UU + (size_t)b * UU;
            float acc = ld_f(p.d0b, tid, f32);
            #pragma unroll 8
            for (int k = 0; k < UU; ++k) {
                float a = 0.5f * (h0[k] + h1[k]);
                acc = fmaf(a, ld_f(p.d0W, (size_t)k * 256 + tid, f32), acc);
            }
            acc = fminf(fmaxf(acc, -1e6f), 1e6f);
            float x = (acc - ld_f(p.bn_mean, tid, f32))
                      * rsqrtf(fmaxf(ld_f(p.bn_var, tid, f32), 0.0f) + 1e-3f)
                      * ld_f(p.bn_gamma, tid, f32) + ld_f(p.bn_beta, tid, f32);
            float al = ld_f(p.alpha, tid, f32);
            hact[tid] = (x > 0.f) ? x : al * x;
        }
        __syncthreads();
        if (tid < 7) {
            float s = ld_f(p.d1b, tid, f32);
            #pragma unroll 8
            for (int k = 0; k < 256; ++k)
                s = fmaf(hact[k], ld_f(p.d1W, k * 7 + tid, f32), s);
            lgts[tid] = fminf(fmaxf(s, -1e6f), 1e6f);
        }
        __syncthreads();
        if (tid == 0) {
            float mx = lgts[0];
            for (int j = 1; j < 7; ++j) mx = fmaxf(mx, lgts[j]);
            float ex[7]; float sum = 0.f;
            for (int j = 0; j < 7; ++j) { ex[j] = __expf(lgts[j] - mx); sum += ex[j]; }
            float inv = 1.0f / sum;
            for (int j = 0; j < 7; ++j) p.out[b * 7 + j] = ex[j] * inv;
        }
    }
}

extern "C" void kernel_launch(void* const* d_in, const int* in_sizes, int n_in,
                              void* d_out, int out_size, void* d_ws, size_t ws_size,
                              hipStream_t stream) {
    (void)in_sizes; (void)n_in; (void)out_size;

    P p;
    p.ids = (const int*)d_in[0];
    p.emb = d_in[1];
    for (int l = 0; l < 3; ++l) {
        p.Wm[0][l] = d_in[2 + l * 3];
        p.Um[0][l] = d_in[3 + l * 3];
        p.bm[0][l] = d_in[4 + l * 3];
        p.Wm[1][l] = d_in[11 + l * 3];
        p.Um[1][l] = d_in[12 + l * 3];
        p.bm[1][l] = d_in[13 + l * 3];
    }
    p.d0W      = d_in[20];
    p.d0b      = d_in[21];
    p.bn_gamma = d_in[22];
    p.bn_beta  = d_in[23];
    p.bn_mean  = d_in[24];
    p.bn_var   = d_in[25];
    p.alpha    = d_in[26];
    p.d1W      = d_in[27];
    p.d1b      = d_in[28];

    char* base = (ws_size >= NEED_WS || g_pool == nullptr) ? (char*)d_ws : (char*)g_pool;
    const size_t OFF_X  = 8192;                                        // flags@0, epoch@4096
    const size_t OFF_H  = OFF_X + (size_t)TT * BB * EMBP * 2;          // +10,485,760
    const size_t OFF_HF = OFF_H + (size_t)3 * 2 * TT * BB * UU * 2;    // +100,663,296
    p.flags = (unsigned int*)base;
    p.epoch = (unsigned int*)(base + 4096);
    p.X     = (unsigned short*)(base + OFF_X);
    p.H     = (unsigned short*)(base + OFF_H);
    p.hf    = (float*)(base + OFF_HF);
    p.out   = (float*)d_out;

    hipMemsetAsync(base, 0, 8192, stream);   // flags+epoch; rest write-before-read
    hipLaunchKernelGGL(bilstm_persistent, dim3(NBLK), dim3(NTHR), 0, stream, p);
}

// Round 6
// 1965.157 us; speedup vs baseline: 1.3083x; 1.3083x over previous
//
#include <hip/hip_runtime.h>
#include <hip/hip_bf16.h>
#include <math.h>

// ---------------- problem constants ----------------
#define TT   128      // timesteps
#define BB   128      // batch
#define UU   512      // LSTM units
#define EMBD 300      // embedding dim
#define EMBP 320      // padded embedding dim (multiple of 32 for MFMA K)
#define NBLK 192      // 2 dir x 3 layers x 32 column-blocks (1 block/CU, 16 h-cols each)
#define DBLK 96       // blocks per direction
#define NTHR 512      // 8 waves: one 16-row tile each -> 2 waves/SIMD
#define BSTR 1032     // Bt row stride el (2064 B)

using bf16x8 = __attribute__((ext_vector_type(8))) short;
using f32x4  = __attribute__((ext_vector_type(4))) float;

// ws layout: flags 768B | epoch @4096 | X 10MB | H 6 slots (write-once!) | hf
#define NEED_WS 111681536ull
static void* g_pool = nullptr;
__attribute__((constructor)) static void alloc_pool() {
    if (hipMalloc(&g_pool, 120ull * 1024ull * 1024ull) != hipSuccess) g_pool = nullptr;
}

__device__ __forceinline__ float b2f(unsigned short u) {
    union { unsigned int i; float f; } v; v.i = ((unsigned int)u) << 16; return v.f;
}
__device__ __forceinline__ unsigned short f2b(float f) {
    union { unsigned int i; float f; } v; v.f = f;
    unsigned int i = v.i;
    return (unsigned short)((i + 0x7fffu + ((i >> 16) & 1u)) >> 16);  // RNE
}
__device__ __forceinline__ unsigned short ld_bf(const void* p, size_t i, int f32) {
    return f32 ? f2b(((const float*)p)[i]) : ((const unsigned short*)p)[i];
}
__device__ __forceinline__ float ld_f(const void* p, size_t i, int f32) {
    return f32 ? ((const float*)p)[i] : b2f(((const unsigned short*)p)[i]);
}
__device__ __forceinline__ float clampz(float x) {
    return fminf(fmaxf(x, -60.0f), 60.0f);
}
__device__ __forceinline__ float sigm(float x)  { return 1.0f / (1.0f + __expf(-x)); }
__device__ __forceinline__ float ssign(float x) { return x / (1.0f + fabsf(x)); }

__device__ __forceinline__ int detect_f32(const void* emb) {
    const unsigned int* w = (const unsigned int*)emb;
    int cnt = 0;
    #pragma unroll
    for (int i = 0; i < 64; ++i) {
        unsigned int e = (w[i] >> 23) & 0xFFu;
        cnt += (e >= 96u && e <= 159u) ? 1 : 0;
    }
    return cnt >= 48;
}

struct P {
    const int* ids;
    const void* emb;
    const void* Wm[2][3];
    const void* Um[2][3];
    const void* bm[2][3];
    const void *d0W, *d0b;
    const void *bn_gamma, *bn_beta, *bn_mean, *bn_var;
    const void *alpha, *d1W, *d1b;
    unsigned short* X;      // [TT][BB][EMBP] bf16 (written once, fence-full barrier after)
    unsigned short* H;      // [3 slots][2 dirs][TT][BB][UU] bf16 — WRITE-ONCE, write-through
    float* hf;              // [2][BB][UU] fp32 — write-through
    unsigned int* flags;    // [NBLK] per-block generation flags
    unsigned int* epoch;    // E[dir][layer] at word (dir*3+layer)*64 (separate lines)
    float* out;             // [BB][7] fp32
};

__device__ __forceinline__ unsigned int ald(const unsigned int* a) {
    return __hip_atomic_load(a, __ATOMIC_RELAXED, __HIP_MEMORY_SCOPE_AGENT);
}
__device__ __forceinline__ void ast(unsigned int* a, unsigned int v) {
    __hip_atomic_store(a, v, __ATOMIC_RELAXED, __HIP_MEMORY_SCOPE_AGENT);
}

// fence-FULL flat barrier (embedding phase + pre-head)
__device__ __forceinline__ void gsync_fence(unsigned int* flags, unsigned int gen) {
    __syncthreads();
    if (threadIdx.x == 0) {
        __threadfence();
        ast(&flags[blockIdx.x], gen);
    }
    if (threadIdx.x < 64) {
        const int i = threadIdx.x;
        for (;;) {
            bool ok = true;
            #pragma unroll
            for (int j = 0; j < NBLK / 64; ++j)
                ok = ok && (ald(&flags[i + j * 64]) >= gen);
            if (__all(ok)) break;
            __builtin_amdgcn_s_sleep(1);
        }
        __threadfence();
    }
    __syncthreads();
}

// step z = [A1 | A2] @ B for this wave's 16-row tile x 4 col-tiles.
// ALL A loads (26..32 x b128) issued upfront into registers -> ONE latency
// exposure per step instead of 8 unroll-batch stalls. B streamed from LDS.
template<int K1T>
__device__ __forceinline__ void mfma_all(
    const unsigned short* __restrict__ a1p,    // A1 row +ko
    const unsigned short* __restrict__ a2p,    // A2 row +ko (nullptr at t==0)
    const unsigned short* __restrict__ bp,     // &Bt[l15][ko]
    f32x4 (&acc)[4])
{
    constexpr int N1 = K1T / 32;
    bf16x8 av1[N1];
    #pragma unroll
    for (int i = 0; i < N1; ++i) av1[i] = *(const bf16x8*)(a1p + i * 32);
    bf16x8 av2[16];
    if (a2p) {
        #pragma unroll
        for (int i = 0; i < 16; ++i) av2[i] = *(const bf16x8*)(a2p + i * 32);
    }
    #pragma unroll
    for (int i = 0; i < N1; ++i) {
        #pragma unroll
        for (int ct = 0; ct < 4; ++ct) {
            bf16x8 bv = *(const bf16x8*)(bp + (size_t)ct * 16 * BSTR + i * 32);
            acc[ct] = __builtin_amdgcn_mfma_f32_16x16x32_bf16(av1[i], bv, acc[ct], 0, 0, 0);
        }
    }
    if (a2p) {
        #pragma unroll
        for (int i = 0; i < 16; ++i) {
            #pragma unroll
            for (int ct = 0; ct < 4; ++ct) {
                bf16x8 bv = *(const bf16x8*)(bp + (size_t)ct * 16 * BSTR + K1T + i * 32);
                acc[ct] = __builtin_amdgcn_mfma_f32_16x16x32_bf16(av2[i], bv, acc[ct], 0, 0, 0);
            }
        }
    }
}

__global__ __launch_bounds__(NTHR, 2) void bilstm_persistent(P p) {
    const int blk = blockIdx.x;
    const int tid = threadIdx.x;

    const int f32 = detect_f32(p.emb);

    __shared__ __align__(16) unsigned short Bt[64][BSTR];  // B panel [n][k] (129 KB)
    __shared__ __align__(16) float zbuf[8][2][16][17];     // per-wave 2-tile z transpose (17 KB)
    __shared__ float hact[256];
    __shared__ float lgts[8];

    // ---------------- phase 0: embedding gather (normal stores) ----------------
    for (int row = blk; row < TT * BB; row += NBLK) {
        int t = row >> 7, b = row & 127;
        int id = p.ids[b * TT + t];
        unsigned short* xr = p.X + (size_t)row * EMBP;
        for (int k2 = tid; k2 < EMBP; k2 += NTHR)
            xr[k2] = (k2 < EMBD) ? ld_bf(p.emb, (size_t)id * EMBD + k2, f32)
                                 : (unsigned short)0;
    }
    gsync_fence(p.flags, 1u);

    // block responsibilities: dir, layer (wavefront-pipelined), 16 h-cols, M=128
    const int dir     = (blk >= DBLK) ? 1 : 0;
    const int rb      = blk - dir * DBLK;
    const int layer   = rb >> 5;             // 0,1,2
    const int dirbase = dir * DBLK;
    const int isagg   = ((rb & 31) == 0);    // one aggregator per (dir,layer)
    const int eL      = (dir * 3 + layer) * 64;
    const int eLm1    = eL - 64;
    const int j0      = (rb & 31) * 16;      // 16 h-cols per block

    const int wv   = tid >> 6;               // wave 0..7, one 16-row tile each
    const int lane = tid & 63;
    const int l15  = lane & 15;
    const int quad = lane >> 4;

    const int row16 = lane & 15;
    const int jp    = (lane >> 4) & 1;
    const int ch    = lane >> 5;

    const int r0   = wv * 16 + l15;
    const int ko   = quad * 8;

    float cS[2][2];                          // cell state: [pp][colA/colB]
    cS[0][0] = cS[0][1] = cS[1][0] = cS[1][1] = 0.0f;

    const size_t seq = (size_t)TT * BB * UU;

    // ---- stage this block's B panel (64 gate-columns, its layer) into LDS — ONCE ----
    const int KW   = (layer == 0) ? EMBD : UU;
    const int K1   = (layer == 0) ? EMBP : UU;
    const int Ktot = K1 + UU;
    const void* Wmat = p.Wm[dir][layer];
    const void* Umat = p.Um[dir][layer];
    const void* bias = p.bm[dir][layer];
    {
        int n = tid >> 3, ks = tid & 7;                          // 8 threads per gate-col row
        int wcol = ((n >> 2) & 3) * UU + j0 + (n >> 4) * 4 + (n & 3);  // gate*512 + j0 + ct*4 + jj
        for (int k2 = ks; k2 < Ktot; k2 += 8) {
            unsigned short v;
            if (k2 < KW)      v = ld_bf(Wmat, (size_t)k2 * 2048 + wcol, f32);
            else if (k2 < K1) v = 0;
            else              v = ld_bf(Umat, (size_t)(k2 - K1) * 2048 + wcol, f32);
            Bt[n][k2] = v;
        }
    }
    // per-lane bias: pass pp handles ct = 2*pp + ch, cols 2*jp, 2*jp+1
    float bz[2][4][2];
    #pragma unroll
    for (int pp = 0; pp < 2; ++pp) {
        const int cb = j0 + (2 * pp + ch) * 4 + 2 * jp;
        #pragma unroll
        for (int g = 0; g < 4; ++g) {
            bz[pp][g][0] = ld_f(bias, g * UU + cb,     f32);
            bz[pp][g][1] = ld_f(bias, g * UU + cb + 1, f32);
        }
    }
    __syncthreads();

    // write-once slots: layer l writes slot l, reads slot l-1
    unsigned short*       Hl  = p.H + (size_t)(layer * 2 + dir) * seq;
    const unsigned short* Hin = (layer > 0) ? (p.H + (size_t)((layer - 1) * 2 + dir) * seq) : nullptr;

    const unsigned short* bp = &Bt[l15][ko];
    float* zbw = &zbuf[wv][0][0][0];         // this wave's private 2x16x17 buffer

    // ------------- wavefront step loop with CHAINED per-layer barrier -------------
    // arrivals of step s store flag s+2; E[dir][l] = published min over the layer.
    for (int s = 0; s < TT + 2; ++s) {
        const int t = s - layer;
        const bool tv = (t >= 0 && t < TT);

        // ---- dependency wait (loop top): need arrivals of step s-1 = value s+1 ----
        if (tv && s > 0) {
            const unsigned int need = (unsigned int)(s + 1);
            if (tid < 64) {
                if (layer == 0) {
                    if (t > 0) {
                        const unsigned int* e = &p.epoch[eL];
                        while (ald(e) < need) __builtin_amdgcn_s_sleep(1);
                    }
                } else {
                    const unsigned int* ein = &p.epoch[eLm1];
                    if (t > 0) {
                        const unsigned int* eo = &p.epoch[eL];
                        while (!((ald(ein) >= need) && (ald(eo) >= need)))
                            __builtin_amdgcn_s_sleep(1);
                    } else {
                        while (ald(ein) < need) __builtin_amdgcn_s_sleep(1);
                    }
                }
            }
            __syncthreads();
        }

        if (tv) {
            const unsigned short* A2r = (t > 0)
                ? (Hl + (size_t)(t - 1) * BB * UU + (size_t)r0 * UU + ko) : nullptr;

            f32x4 acc[4];
            #pragma unroll
            for (int ct = 0; ct < 4; ++ct) acc[ct] = f32x4{0.f, 0.f, 0.f, 0.f};

            if (layer == 0) {
                int tx = dir ? (TT - 1 - t) : t;
                const unsigned short* A1 = p.X + (size_t)tx * BB * EMBP;
                mfma_all<EMBP>(A1 + (size_t)r0 * EMBP + ko, A2r, bp, acc);
            } else {
                const unsigned short* A1 = Hin + (size_t)t * BB * UU;
                mfma_all<UU>(A1 + (size_t)r0 * UU + ko, A2r, bp, acc);
            }

            // ---- gates, wave-private LDS transpose, 2 ct per pass (NO __syncthreads) ----
            // D layout: col = lane&15, row = quad*4 + reg  (m89-verified)
            #pragma unroll
            for (int pp = 0; pp < 2; ++pp) {
                #pragma unroll
                for (int cth = 0; cth < 2; ++cth) {
                    const int ct = pp * 2 + cth;
                    #pragma unroll
                    for (int r = 0; r < 4; ++r)
                        zbw[cth * 272 + (quad * 4 + r) * 17 + l15] = acc[ct][r];
                }
                // in-order DS pipe: wave-level write->read needs no barrier
                const int zb0 = ch * 272 + row16 * 17 + 2 * jp;
                float ziA = clampz(zbw[zb0 +  0] + bz[pp][0][0]);
                float zfA = clampz(zbw[zb0 +  4] + bz[pp][1][0]);
                float zgA = clampz(zbw[zb0 +  8] + bz[pp][2][0]);
                float zoA = clampz(zbw[zb0 + 12] + bz[pp][3][0]);
                float ziB = clampz(zbw[zb0 +  1] + bz[pp][0][1]);
                float zfB = clampz(zbw[zb0 +  5] + bz[pp][1][1]);
                float zgB = clampz(zbw[zb0 +  9] + bz[pp][2][1]);
                float zoB = clampz(zbw[zb0 + 13] + bz[pp][3][1]);
                float cpA = (t == 0) ? 0.0f : cS[pp][0];
                float cpB = (t == 0) ? 0.0f : cS[pp][1];
                float cnA = sigm(zfA) * cpA + sigm(ziA) * ssign(zgA);
                float cnB = sigm(zfB) * cpB + sigm(ziB) * ssign(zgB);
                cS[pp][0] = cnA; cS[pp][1] = cnB;
                float hA = sigm(zoA) * ssign(cnA);
                float hB = sigm(zoB) * ssign(cnB);
                // packed write-through store (device-coherent; never dirty in L2)
                const int R   = wv * 16 + row16;
                const int col = j0 + (2 * pp + ch) * 4 + 2 * jp;
                unsigned int pk = (unsigned int)f2b(hA) | ((unsigned int)f2b(hB) << 16);
                __hip_atomic_store((unsigned int*)&Hl[(size_t)t * BB * UU + (size_t)R * UU + col],
                                   pk, __ATOMIC_RELAXED, __HIP_MEMORY_SCOPE_AGENT);
                if (layer == 2 && t == TT - 1) {
                    size_t o = (size_t)dir * BB * UU + (size_t)R * UU + col;
                    __hip_atomic_store(&p.hf[o],     hA, __ATOMIC_RELAXED, __HIP_MEMORY_SCOPE_AGENT);
                    __hip_atomic_store(&p.hf[o + 1], hB, __ATOMIC_RELAXED, __HIP_MEMORY_SCOPE_AGENT);
                }
            }
        }

        // ---- arrive: __syncthreads drains this block's stores (vmcnt 0) ----
        __syncthreads();
        if (tid == 0) ast(&p.flags[blk], (unsigned int)(s + 2));

        // ---- aggregator: publish layer epoch once all 32 siblings arrived ----
        if (isagg) {
            const unsigned int g = (unsigned int)(s + 2);
            if (tid < 64) {
                const unsigned int* f = p.flags + dirbase + layer * 32 + (tid & 31);
                while (!__all(ald(f) >= g)) __builtin_amdgcn_s_sleep(1);
            }
            if (tid == 0) ast(&p.epoch[eL], g);
        }
    }

    gsync_fence(p.flags, (unsigned int)(TT + 4));   // both dirs' hf complete before head

    // ---------------- head: block b handles batch row b (all fp32) ----------------
    if (blk < BB) {
        const int b = blk;
        if (tid < 256) {
            const float* h0 = p.hf + (size_t)b * UU;
            const float* h1 = p.hf + (size_t)BB * UU + (size_t)b * UU;
            float acc = ld_f(p.d0b, tid, f32);
            #pragma unroll 8
            for (int k = 0; k < UU; ++k) {
                float a = 0.5f * (h0[k] + h1[k]);
                acc = fmaf(a, ld_f(p.d0W, (size_t)k * 256 + tid, f32), acc);
            }
            acc = fminf(fmaxf(acc, -1e6f), 1e6f);
            float x = (acc - ld_f(p.bn_mean, tid, f32))
                      * rsqrtf(fmaxf(ld_f(p.bn_var, tid, f32), 0.0f) + 1e-3f)
                      * ld_f(p.bn_gamma, tid, f32) + ld_f(p.bn_beta, tid, f32);
            float al = ld_f(p.alpha, tid, f32);
            hact[tid] = (x > 0.f) ? x : al * x;
        }
        __syncthreads();
        if (tid < 7) {
            float s = ld_f(p.d1b, tid, f32);
            #pragma unroll 8
            for (int k = 0; k < 256; ++k)
                s = fmaf(hact[k], ld_f(p.d1W, k * 7 + tid, f32), s);
            lgts[tid] = fminf(fmaxf(s, -1e6f), 1e6f);
        }
        __syncthreads();
        if (tid == 0) {
            float mx = lgts[0];
            for (int j = 1; j < 7; ++j) mx = fmaxf(mx, lgts[j]);
            float ex[7]; float sum = 0.f;
            for (int j = 0; j < 7; ++j) { ex[j] = __expf(lgts[j] - mx); sum += ex[j]; }
            float inv = 1.0f / sum;
            for (int j = 0; j < 7; ++j) p.out[b * 7 + j] = ex[j] * inv;
        }
    }
}

extern "C" void kernel_launch(void* const* d_in, const int* in_sizes, int n_in,
                              void* d_out, int out_size, void* d_ws, size_t ws_size,
                              hipStream_t stream) {
    (void)in_sizes; (void)n_in; (void)out_size;

    P p;
    p.ids = (const int*)d_in[0];
    p.emb = d_in[1];
    for (int l = 0; l < 3; ++l) {
        p.Wm[0][l] = d_in[2 + l * 3];
        p.Um[0][l] = d_in[3 + l * 3];
        p.bm[0][l] = d_in[4 + l * 3];
        p.Wm[1][l] = d_in[11 + l * 3];
        p.Um[1][l] = d_in[12 + l * 3];
        p.bm[1][l] = d_in[13 + l * 3];
    }
    p.d0W      = d_in[20];
    p.d0b      = d_in[21];
    p.bn_gamma = d_in[22];
    p.bn_beta  = d_in[23];
    p.bn_mean  = d_in[24];
    p.bn_var   = d_in[25];
    p.alpha    = d_in[26];
    p.d1W      = d_in[27];
    p.d1b      = d_in[28];

    char* base = (ws_size >= NEED_WS || g_pool == nullptr) ? (char*)d_ws : (char*)g_pool;
    const size_t OFF_X  = 8192;                                        // flags@0, epoch@4096
    const size_t OFF_H  = OFF_X + (size_t)TT * BB * EMBP * 2;          // +10,485,760
    const size_t OFF_HF = OFF_H + (size_t)3 * 2 * TT * BB * UU * 2;    // +100,663,296
    p.flags = (unsigned int*)base;
    p.epoch = (unsigned int*)(base + 4096);
    p.X     = (unsigned short*)(base + OFF_X);
    p.H     = (unsigned short*)(base + OFF_H);
    p.hf    = (float*)(base + OFF_HF);
    p.out   = (float*)d_out;

    hipMemsetAsync(base, 0, 8192, stream);   // flags+epoch; rest write-before-read
    hipLaunchKernelGGL(bilstm_persistent, dim3(NBLK), dim3(NTHR), 0, stream, p);
}